// Round 4
// baseline (958.660 us; speedup 1.0000x reference)
//
#include <hip/hip_runtime.h>
#include <cstdint>
#include <cstddef>

typedef short short8 __attribute__((ext_vector_type(8)));
typedef float floatx4 __attribute__((ext_vector_type(4)));
typedef unsigned short u16;

__device__ __forceinline__ u16 f2bf(float f) {
    unsigned u = __float_as_uint(f);
    u += 0x7FFFu + ((u >> 16) & 1u);
    return (u16)(u >> 16);
}
__device__ __forceinline__ float bf2f(u16 h) {
    return __uint_as_float(((unsigned)h) << 16);
}

// async global->LDS, 16B per lane; LDS base must be wave-uniform.
__device__ __forceinline__ void gload_lds16(const u16* g, u16* l) {
    __builtin_amdgcn_global_load_lds(
        (const __attribute__((address_space(1))) void*)g,
        (__attribute__((address_space(3))) void*)l, 16, 0, 0);
}

// ---------------------------------------------------------------------------
// Kernel 1: x [4][72][32][32][32] f32 (NCDHW)  ->  xt [4][32][32][32][72] bf16
// ---------------------------------------------------------------------------
__global__ __launch_bounds__(256) void k_transpose_x(const float* __restrict__ x,
                                                     u16* __restrict__ xt) {
    __shared__ float tile[72 * 33];
    const int bx = blockIdx.x;               // ((b*32+d)*32+h)
    const int tid = threadIdx.x;
    const int b = bx >> 10, d = (bx >> 5) & 31, h = bx & 31;
    const float* src = x + (size_t)b * 72 * 32768 + d * 1024 + h * 32;
    for (int e = tid; e < 2304; e += 256) {
        int ci = e >> 5, w = e & 31;
        tile[ci * 33 + w] = src[(size_t)ci * 32768 + w];
    }
    __syncthreads();
    u16* dst = xt + (size_t)bx * 2304;
    for (int e = tid; e < 2304; e += 256) {
        int w = e / 72, ci = e - w * 72;
        dst[e] = f2bf(tile[ci * 33 + w]);
    }
}

// ---------------------------------------------------------------------------
// Kernel 2: W [176][72][5][5][5] f32 -> wt bf16 per-lane B-fragment layout:
//   wt[kd][kh][kblk(12)][nblk(11)][lane(64)][8]   (linear in kk = kh*12+kb)
// ---------------------------------------------------------------------------
__global__ __launch_bounds__(256) void k_prep_w(const float* __restrict__ W,
                                                u16* __restrict__ wt) {
    const int gid = blockIdx.x * 256 + threadIdx.x;   // 825*256 = 211200 = 3300 frags * 64
    const int frag = gid >> 6, lane = gid & 63;
    const int nb = frag % 11;
    int t = frag / 11;
    const int kb = t % 12;
    t = t / 12;
    const int kh = t % 5, kd = t / 5;
    const int n = lane & 15, q8 = (lane >> 4) * 8;
    const int co = nb * 16 + n;
    u16 v[8] __attribute__((aligned(16)));
    #pragma unroll
    for (int j = 0; j < 8; ++j) {
        int k = kb * 32 + q8 + j;
        u16 r = 0;
        if (k < 360) {
            int kw = k / 72, ci = k - kw * 72;
            r = f2bf(W[((size_t)co * 72 + ci) * 125 + kd * 25 + kh * 5 + kw]);
        }
        v[j] = r;
    }
    *(uint4*)(wt + (size_t)gid * 8) = *(const uint4*)v;
}

// ---------------------------------------------------------------------------
// Kernel 3: implicit-GEMM conv + fused gating, 6-step barrier-free regions.
// Grid 256 = (b:4, d:32, ht:2), XCD-swizzled. Block: 512 threads = 8 waves.
// Block tile: 16 h-rows x 32 w x 176 co; wave: 2 h-rows x 32 w x 176 co.
//  - A fragments: per-lane predicated loads DIRECT from global xt (L2-resident
//    per XCD thanks to the swizzle), register-double-buffered 1 step ahead.
//    Zero-halo semantics reproduced via bounds predication (e in [0,2304),
//    row in [0,32)); k>=360 tail is harmless because wt is zero there.
//  - B: two 6-step half-slabs (2 x 66 KB) in LDS via global_load_lds; region
//    H computes 6 steps from buf H%2 while staging H+1 into buf (H+1)%2.
//    Barriers only at region boundaries: 11/kd instead of 30 -> waves drift
//    within a region and LDS/MFMA pipes overlap across waves.
// ---------------------------------------------------------------------------
#define MFMA_BF16 __builtin_amdgcn_mfma_f32_16x16x32_bf16

// Load the 4 A-fragments for (kh_, kb_) into short8 vars A_0..A_3.
#define LOADA(A_, kh_, kb_) do {                                                   \
    const int hp_ = h0 + 2 * wv + (kh_) - 2;                                       \
    const int e_  = laneE + (kb_) * 32;                                            \
    const bool r0_ = (unsigned)hp_ < 32u;                                          \
    const bool r1_ = (unsigned)(hp_ + 1) < 32u;                                    \
    const bool c0_ = (unsigned)e_ < 2304u;                                         \
    const bool c1_ = (unsigned)(e_ + 1152) < 2304u;                                \
    const u16* rp_ = xslice + (size_t)hp_ * 2304 + e_;                             \
    short8 t0_ = (short8)0, t1_ = (short8)0, t2_ = (short8)0, t3_ = (short8)0;     \
    if (r0_ && c0_) t0_ = *(const short8*)(rp_);                                   \
    if (r0_ && c1_) t1_ = *(const short8*)(rp_ + 1152);                            \
    if (r1_ && c0_) t2_ = *(const short8*)(rp_ + 2304);                            \
    if (r1_ && c1_) t3_ = *(const short8*)(rp_ + 2304 + 1152);                     \
    A_##0 = t0_; A_##1 = t1_; A_##2 = t2_; A_##3 = t3_;                            \
} while (0)

// One kb-step: 11 B LDS reads + 44 MFMAs, consuming A-set A_.
#define CSTEPB(A_, bofs_) do {                                                     \
    const u16* bb_ = bbB + (bofs_);                                                \
    _Pragma("unroll")                                                              \
    for (int j = 0; j < 11; ++j) {                                                 \
        short8 bv = *(const short8*)(bb_ + j * 512);                               \
        acc[0][j] = MFMA_BF16(A_##0, bv, acc[0][j], 0, 0, 0);                      \
        acc[1][j] = MFMA_BF16(A_##1, bv, acc[1][j], 0, 0, 0);                      \
        acc[2][j] = MFMA_BF16(A_##2, bv, acc[2][j], 0, 0, 0);                      \
        acc[3][j] = MFMA_BF16(A_##3, bv, acc[3][j], 0, 0, 0);                      \
    }                                                                              \
} while (0)

// Stage half-slab H_ (6 kb-steps x 11 nb = 66 KiB) into LDS buf H_%2.
// 66 chunks of 1024 B over 8 waves (waves 0,1 take a 9th chunk).
#define STAGE_HALF(H_) do {                                                        \
    const int kk0_ = (H_) * 6;                                                     \
    u16* db_ = sB + ((H_) & 1) * 33792;                                            \
    _Pragma("unroll")                                                              \
    for (int cc = 0; cc < 9; ++cc) {                                               \
        const int c_ = wv + cc * 8;                                                \
        if (c_ < 66) {                                                             \
            const int kbl_ = c_ / 11, nb_ = c_ - kbl_ * 11;                        \
            gload_lds16(wt_kd + (size_t)(kk0_ + kbl_) * 5632 + nb_ * 512 + lane * 8, \
                        db_ + kbl_ * 5632 + nb_ * 512);                            \
        }                                                                          \
    }                                                                              \
} while (0)

__global__ __launch_bounds__(512, 2) void k_conv(const u16* __restrict__ xt,
                                                 const u16* __restrict__ wt,
                                                 const float* __restrict__ scalar_bias,
                                                 const float* __restrict__ gate_bias,
                                                 u16* __restrict__ zt) {
    __shared__ __align__(16) u16 sB[2 * 33792];   // 2 x 67,584 B = 135,168 B
    const int bx = blockIdx.x;
    // XCD-aware swizzle (256 = 8 XCD x 32): contiguous (b,d,ht) range per XCD
    // -> per-XCD xt working set ~3.3 MB, L2-resident.
    const int logical = (bx & 7) * 32 + (bx >> 3);
    const int ht = logical & 1, d = (logical >> 1) & 31, b = logical >> 6;
    const int h0 = ht * 16;
    const int tid = threadIdx.x, lane = tid & 63, wv = tid >> 6;
    const int c15 = lane & 15, q = lane >> 4;

    floatx4 acc[4][11];
    #pragma unroll
    for (int i = 0; i < 4; ++i) {
        #pragma unroll
        for (int j = 0; j < 11; ++j) acc[i][j] = (floatx4){0.f, 0.f, 0.f, 0.f};
    }

    const int laneE = c15 * 72 + q * 8 - 144;   // in-row element offset (may be <0)
    short8 XA0, XA1, XA2, XA3, YA0, YA1, YA2, YA3;

    for (int kd = 0; kd < 5; ++kd) {
        const int dp = d + kd - 2;
        if (dp < 0 || dp >= 32) continue;            // block-uniform
        const u16* wt_kd  = wt + (size_t)kd * 5 * 67584;   // per (kd,kh): 12*11*512 u16
        const u16* xslice = xt + (size_t)((b * 32 + dp) * 32) * 2304;

        LOADA(XA, 0, 0);       // A for first step (in flight across stage+barrier)
        STAGE_HALF(0);
        __syncthreads();       // drains stage + A prologue loads

        #pragma unroll 1
        for (int H = 0; H < 10; ++H) {
            if (H < 9) STAGE_HALF(H + 1);            // in flight across this region
            const int kh  = H >> 1,        kb0  = (H & 1) * 6;
            const int khn = (H + 1) >> 1,  kb0n = ((H + 1) & 1) * 6;
            const u16* bbB = sB + (H & 1) * 33792 + lane * 8;
            LOADA(YA, kh, kb0 + 1);  CSTEPB(XA, 0 * 5632);
            LOADA(XA, kh, kb0 + 2);  CSTEPB(YA, 1 * 5632);
            LOADA(YA, kh, kb0 + 3);  CSTEPB(XA, 2 * 5632);
            LOADA(XA, kh, kb0 + 4);  CSTEPB(YA, 3 * 5632);
            LOADA(YA, kh, kb0 + 5);  CSTEPB(XA, 4 * 5632);
            LOADA(XA, khn, kb0n);    CSTEPB(YA, 5 * 5632);   // cross-region prefetch
            __syncthreads();   // region boundary: drains next half's stage (free)
        }
    }

    // ---- epilogue: fused gate + bf16 store to zt ----
    // C/D layout: col(co) = lane&15, row(pos) = q*4 + reg.
    const float sb = scalar_bias[c15];
    int   slA[9];
    float gbA[9];
    #pragma unroll
    for (int nb = 1; nb <= 8; ++nb) {
        int idx = (nb - 1) * 16 + c15;                       // co_f - 16
        int mul = (nb <= 3) ? (idx / 3) : (16 + (idx - 48) / 5);
        slA[nb] = (lane & 48) | (mul & 15);
        gbA[nb] = gate_bias[mul];
    }
    #pragma unroll
    for (int mi = 0; mi < 4; ++mi) {
        const int hl = 2 * wv + (mi >> 1);
        const int wh = mi & 1;
        const size_t zrow0 = (size_t)((b * 32 + d) * 32 + (h0 + hl)) * 32;
        #pragma unroll
        for (int r = 0; r < 4; ++r) {
            const int w = wh * 16 + q * 4 + r;
            u16* zp = zt + (zrow0 + w) * 144;
            zp[c15] = f2bf(fmaxf(acc[mi][0][r] + sb, 0.f));   // scalar field: relu+bias
            const float g9v  = acc[mi][9][r];
            const float g10v = acc[mi][10][r];
            #pragma unroll
            for (int nb = 1; nb <= 8; ++nb) {
                float ys = __shfl((nb <= 3) ? g9v : g10v, slA[nb], 64);
                float g  = 1.f / (1.f + __expf(-(ys + gbA[nb])));
                zp[nb * 16 + c15] = f2bf(acc[mi][nb][r] * g);
            }
        }
    }
}

// ---------------------------------------------------------------------------
// Kernel 4: stride-2 5x5x5 Gaussian low-pass.
// zt [b][d][h][w][144] bf16 -> out [4][144][16][16][16] f32 (NCDHW).
// ---------------------------------------------------------------------------
__global__ __launch_bounds__(256) void k_lowpass(const u16* __restrict__ zt,
                                                 float* __restrict__ out) {
    const int gid = blockIdx.x * 256 + threadIdx.x;   // 1152*256 = 294912
    const int row = gid / 288;
    const int it  = gid - row * 288;
    const int c8 = it >> 4, ow = it & 15;
    const int oh = row & 15, od = (row >> 4) & 15, b = row >> 8;
    const float lw[5] = {0.03208210f, 0.23705644f, 0.46172277f, 0.23705644f, 0.03208210f};
    float a[8];
    #pragma unroll
    for (int j = 0; j < 8; ++j) a[j] = 0.f;
    for (int kd = 0; kd < 5; ++kd) {
        const int dz = 2 * od + kd - 2;
        if (dz < 0 || dz >= 32) continue;
        for (int kh = 0; kh < 5; ++kh) {
            const int hz = 2 * oh + kh - 2;
            if (hz < 0 || hz >= 32) continue;
            const float whd = lw[kd] * lw[kh];
            const u16* base = zt + (size_t)((b * 32 + dz) * 32 + hz) * 32 * 144 + c8 * 8;
            #pragma unroll
            for (int kw = 0; kw < 5; ++kw) {
                const int wz = 2 * ow + kw - 2;
                if (wz < 0 || wz >= 32) continue;
                const float wt3 = whd * lw[kw];
                u16 v[8] __attribute__((aligned(16)));
                *(uint4*)v = *(const uint4*)(base + (size_t)wz * 144);
                #pragma unroll
                for (int j = 0; j < 8; ++j) a[j] += wt3 * bf2f(v[j]);
            }
        }
    }
    const int c0 = c8 * 8;
    float* op = out + ((size_t)b * 144 + c0) * 4096 + od * 256 + oh * 16 + ow;
    #pragma unroll
    for (int j = 0; j < 8; ++j) op[(size_t)j * 4096] = a[j];
}

// ---------------------------------------------------------------------------
extern "C" void kernel_launch(void* const* d_in, const int* in_sizes, int n_in,
                              void* d_out, int out_size, void* d_ws, size_t ws_size,
                              hipStream_t stream) {
    const float* x  = (const float*)d_in[0];   // 4*72*32^3
    const float* W  = (const float*)d_in[1];   // 176*72*125
    const float* sb = (const float*)d_in[2];   // 16
    const float* gb = (const float*)d_in[3];   // 32
    float* out = (float*)d_out;                // 4*144*16^3 f32

    char* ws = (char*)d_ws;
    u16* xt = (u16*)(ws);                      // 18,874,368 B
    u16* wt = (u16*)(ws + 18874368);           //  3,379,200 B
    u16* zt = (u16*)(ws + 22253568);           // 37,748,736 B  (total ~60 MB)

    hipLaunchKernelGGL(k_transpose_x, dim3(4096), dim3(256), 0, stream, x, xt);
    hipLaunchKernelGGL(k_prep_w,      dim3(825),  dim3(256), 0, stream, W, wt);
    hipLaunchKernelGGL(k_conv,        dim3(256),  dim3(512), 0, stream, xt, wt, sb, gb, zt);
    hipLaunchKernelGGL(k_lowpass,     dim3(1152), dim3(256), 0, stream, zt, out);
}

// Round 5
// 570.949 us; speedup vs baseline: 1.6791x; 1.6791x over previous
//
#include <hip/hip_runtime.h>
#include <cstdint>
#include <cstddef>

typedef short short8 __attribute__((ext_vector_type(8)));
typedef float floatx4 __attribute__((ext_vector_type(4)));
typedef unsigned short u16;

__device__ __forceinline__ u16 f2bf(float f) {
    unsigned u = __float_as_uint(f);
    u += 0x7FFFu + ((u >> 16) & 1u);
    return (u16)(u >> 16);
}
__device__ __forceinline__ float bf2f(u16 h) {
    return __uint_as_float(((unsigned)h) << 16);
}

// async global->LDS, 16B per lane; LDS base must be wave-uniform (HW adds lane*16B).
__device__ __forceinline__ void gload_lds16(const u16* g, u16* l) {
    __builtin_amdgcn_global_load_lds(
        (const __attribute__((address_space(1))) void*)g,
        (__attribute__((address_space(3))) void*)l, 16, 0, 0);
}

// ---------------------------------------------------------------------------
// Kernel 1: x [4][72][32][32][32] f32 (NCDHW)  ->  xt [4][32][32][32][72] bf16
// ---------------------------------------------------------------------------
__global__ __launch_bounds__(256) void k_transpose_x(const float* __restrict__ x,
                                                     u16* __restrict__ xt) {
    __shared__ float tile[72 * 33];
    const int bx = blockIdx.x;               // ((b*32+d)*32+h)
    const int tid = threadIdx.x;
    const int b = bx >> 10, d = (bx >> 5) & 31, h = bx & 31;
    const float* src = x + (size_t)b * 72 * 32768 + d * 1024 + h * 32;
    for (int e = tid; e < 2304; e += 256) {
        int ci = e >> 5, w = e & 31;
        tile[ci * 33 + w] = src[(size_t)ci * 32768 + w];
    }
    __syncthreads();
    u16* dst = xt + (size_t)bx * 2304;
    for (int e = tid; e < 2304; e += 256) {
        int w = e / 72, ci = e - w * 72;
        dst[e] = f2bf(tile[ci * 33 + w]);
    }
}

// ---------------------------------------------------------------------------
// Kernel 2: W [176][72][5][5][5] f32 -> wt bf16 per-lane B-fragment layout:
//   wt[kd][kh][kblk(12)][nblk(11)][lane(64)][8]   (linear in kk = kh*12+kb)
// ---------------------------------------------------------------------------
__global__ __launch_bounds__(256) void k_prep_w(const float* __restrict__ W,
                                                u16* __restrict__ wt) {
    const int gid = blockIdx.x * 256 + threadIdx.x;   // 825*256 = 211200 = 3300 frags * 64
    const int frag = gid >> 6, lane = gid & 63;
    const int nb = frag % 11;
    int t = frag / 11;
    const int kb = t % 12;
    t = t / 12;
    const int kh = t % 5, kd = t / 5;
    const int n = lane & 15, q8 = (lane >> 4) * 8;
    const int co = nb * 16 + n;
    u16 v[8] __attribute__((aligned(16)));
    #pragma unroll
    for (int j = 0; j < 8; ++j) {
        int k = kb * 32 + q8 + j;
        u16 r = 0;
        if (k < 360) {
            int kw = k / 72, ci = k - kw * 72;
            r = f2bf(W[((size_t)co * 72 + ci) * 125 + kd * 25 + kh * 5 + kw]);
        }
        v[j] = r;
    }
    *(uint4*)(wt + (size_t)gid * 8) = *(const uint4*)v;
}

// ---------------------------------------------------------------------------
// Kernel 3: implicit-GEMM conv + fused gating, TWO barrier-domains per CU.
// Grid 1024 = (b:4, d:32, ht:4, cb:2), XCD-swizzled. Block: 256 thr = 4 waves.
// Block tile: 8 h-rows x 32 w x co-subset; wave: 2 h-rows x 32 w x co-subset.
// Co-split is gate-self-contained:
//   cb0: frags nb {0,1,2,3, 9}  (scalar+dim3 fields + their gates)   NF=5
//   cb1: frags nb {4,5,6,7,8,10}(dim5 fields + their gates)          NF=6
// LDS/block = A-tile 62,208 B + B-ring 3x6,144 B = 80,640 B -> 2 blocks/CU.
// The two co-resident blocks have unaligned barrier phases, so one block's
// MFMA burst overlaps the other's LDS-read burst (round-3 was SUM of the
// two phases in a single 8-wave barrier domain).
// Registers: acc <= 96 AGPR (vs 176) -> no spill risk.
// ---------------------------------------------------------------------------
#define LP 2592
#define MFMA_BF16 __builtin_amdgcn_mfma_f32_16x16x32_bf16

template<int CB>
__device__ __forceinline__ void conv_body(const u16* __restrict__ xt,
                                          const u16* __restrict__ wt,
                                          const float* __restrict__ scalar_bias,
                                          const float* __restrict__ gate_bias,
                                          u16* __restrict__ zt,
                                          u16* sx, u16* sB,
                                          int b, int d, int h0,
                                          int tid, int lane, int wv,
                                          int c15, int q) {
    constexpr int NF = CB ? 6 : 5;

    floatx4 acc[4][NF];
    #pragma unroll
    for (int i = 0; i < 4; ++i) {
        #pragma unroll
        for (int j = 0; j < NF; ++j) acc[i][j] = (floatx4){0.f, 0.f, 0.f, 0.f};
    }

    const int laneA = c15 * 72 + q * 8;

    for (int kd = 0; kd < 5; ++kd) {
        const int dp = d + kd - 2;
        if (dp < 0 || dp >= 32) continue;            // block-uniform
        const u16* wt_kd = wt + (size_t)kd * 5 * 67584;   // 12*11*512 u16 per (kd,kh)

        // ---- stage A d-slice into LDS (zero-fill halos) ----
        const u16* srcbase = xt + (size_t)((b * 32 + dp) * 32) * 2304;
        for (int idx = tid; idx < 12 * 324; idx += 256) {
            int r = idx / 324, c = idx - r * 324;
            int hp = h0 + r - 2;
            uint4 val = make_uint4(0u, 0u, 0u, 0u);
            if (hp >= 0 && hp < 32 && c >= 18 && c < 306)
                val = *(const uint4*)(srcbase + (size_t)hp * 2304 + (c * 8 - 144));
            *(uint4*)(&sx[r * LP + c * 8]) = val;
        }

        // stage helper: frag f of step kk -> ring slot s (wave wv takes f=wv, f=wv+4)
        auto stage = [&](int kk, int s) {
            #pragma unroll
            for (int t = 0; t < 2; ++t) {
                const int f = wv + t * 4;
                if (f < NF) {
                    const int nb = CB ? ((f == 5) ? 10 : (f + 4))
                                      : ((f == 4) ? 9 : f);
                    gload_lds16(wt_kd + (size_t)kk * 5632 + nb * 512 + lane * 8,
                                sB + s * 3072 + f * 512);
                }
            }
        };

        stage(0, 0);
        stage(1, 1);
        __syncthreads();   // drains A staging + first two B stages

        // ---- 60 kb-steps, 3-slot ring, barrier per step ----
        int kh = 0, kb = 0, s0 = 0;
        #pragma unroll 1
        for (int kk = 0; kk < 60; ++kk) {
            int s2 = s0 + 2; if (s2 >= 3) s2 -= 3;
            if (kk < 58) stage(kk + 2, s2);          // issue-early, 2 steps ahead
            const u16* ap = sx + (2 * wv + kh) * LP + laneA + kb * 32;
            short8 A0 = *(const short8*)(ap);
            short8 A1 = *(const short8*)(ap + 1152);
            short8 A2 = *(const short8*)(ap + LP);
            short8 A3 = *(const short8*)(ap + LP + 1152);
            const u16* bb = sB + s0 * 3072 + lane * 8;
            __builtin_amdgcn_s_setprio(1);
            #pragma unroll
            for (int f = 0; f < NF; ++f) {
                short8 bv = *(const short8*)(bb + f * 512);
                acc[0][f] = MFMA_BF16(A0, bv, acc[0][f], 0, 0, 0);
                acc[1][f] = MFMA_BF16(A1, bv, acc[1][f], 0, 0, 0);
                acc[2][f] = MFMA_BF16(A2, bv, acc[2][f], 0, 0, 0);
                acc[3][f] = MFMA_BF16(A3, bv, acc[3][f], 0, 0, 0);
            }
            __builtin_amdgcn_s_setprio(0);
            __syncthreads();
            if (++kb == 12) { kb = 0; ++kh; }
            if (++s0 == 3) s0 = 0;
        }
    }

    // ---- epilogue: fused gate + bf16 store to zt ----
    // C/D layout: col(co within frag) = lane&15, row(pos) = q*4 + reg.
    constexpr int GF = NF - 1;                 // gate frag (nb 9 or 10)
    constexpr int NGATED = CB ? 5 : 3;
    int   slA[NGATED];
    float gbA[NGATED];
    #pragma unroll
    for (int j = 0; j < NGATED; ++j) {
        const int nb = CB ? (j + 4) : (j + 1);
        const int idx = (nb - 1) * 16 + c15;                 // co_f - 16
        const int mul = (nb <= 3) ? (idx / 3) : (16 + (idx - 48) / 5);
        slA[j] = (lane & 48) | (mul & 15);
        gbA[j] = gate_bias[mul];
    }
    const float sb = CB ? 0.f : scalar_bias[c15];
    #pragma unroll
    for (int mi = 0; mi < 4; ++mi) {
        const int hl = 2 * wv + (mi >> 1);
        const int wh = mi & 1;
        const size_t zrow0 = (size_t)((b * 32 + d) * 32 + (h0 + hl)) * 32;
        #pragma unroll
        for (int r = 0; r < 4; ++r) {
            const int w = wh * 16 + q * 4 + r;
            u16* zp = zt + (zrow0 + w) * 144;
            const float gv = acc[mi][GF][r];
            if (CB == 0)
                zp[c15] = f2bf(fmaxf(acc[mi][0][r] + sb, 0.f));  // scalar: relu+bias
            #pragma unroll
            for (int j = 0; j < NGATED; ++j) {
                const int nb = CB ? (j + 4) : (j + 1);
                float ys = __shfl(gv, slA[j], 64);
                float g  = 1.f / (1.f + __expf(-(ys + gbA[j])));
                zp[nb * 16 + c15] = f2bf(acc[mi][CB ? j : (j + 1)][r] * g);
            }
        }
    }
}

__global__ __launch_bounds__(256, 2) void k_conv(const u16* __restrict__ xt,
                                                 const u16* __restrict__ wt,
                                                 const float* __restrict__ scalar_bias,
                                                 const float* __restrict__ gate_bias,
                                                 u16* __restrict__ zt) {
    __shared__ __align__(16) u16 sx[12 * LP];    // 62,208 B
    __shared__ __align__(16) u16 sB[3 * 3072];   // 18,432 B   (total 80,640 B)
    const int bx = blockIdx.x;
    // XCD swizzle (1024 = 8 XCD x 128); (ht,cb) fastest for xt L2 locality.
    const int swz = (bx & 7) * 128 + (bx >> 3);
    const int cb = swz & 1, ht = (swz >> 1) & 3, d = (swz >> 3) & 31, b = swz >> 8;
    const int h0 = ht * 8;
    const int tid = threadIdx.x, lane = tid & 63, wv = tid >> 6;
    const int c15 = lane & 15, q = lane >> 4;

    if (cb == 0)
        conv_body<0>(xt, wt, scalar_bias, gate_bias, zt, sx, sB, b, d, h0, tid, lane, wv, c15, q);
    else
        conv_body<1>(xt, wt, scalar_bias, gate_bias, zt, sx, sB, b, d, h0, tid, lane, wv, c15, q);
}

// ---------------------------------------------------------------------------
// Kernel 4: stride-2 5x5x5 Gaussian low-pass.
// zt [b][d][h][w][144] bf16 -> out [4][144][16][16][16] f32 (NCDHW).
// ---------------------------------------------------------------------------
__global__ __launch_bounds__(256) void k_lowpass(const u16* __restrict__ zt,
                                                 float* __restrict__ out) {
    const int gid = blockIdx.x * 256 + threadIdx.x;   // 1152*256 = 294912
    const int row = gid / 288;
    const int it  = gid - row * 288;
    const int c8 = it >> 4, ow = it & 15;
    const int oh = row & 15, od = (row >> 4) & 15, b = row >> 8;
    const float lw[5] = {0.03208210f, 0.23705644f, 0.46172277f, 0.23705644f, 0.03208210f};
    float a[8];
    #pragma unroll
    for (int j = 0; j < 8; ++j) a[j] = 0.f;
    for (int kd = 0; kd < 5; ++kd) {
        const int dz = 2 * od + kd - 2;
        if (dz < 0 || dz >= 32) continue;
        for (int kh = 0; kh < 5; ++kh) {
            const int hz = 2 * oh + kh - 2;
            if (hz < 0 || hz >= 32) continue;
            const float whd = lw[kd] * lw[kh];
            const u16* base = zt + (size_t)((b * 32 + dz) * 32 + hz) * 32 * 144 + c8 * 8;
            #pragma unroll
            for (int kw = 0; kw < 5; ++kw) {
                const int wz = 2 * ow + kw - 2;
                if (wz < 0 || wz >= 32) continue;
                const float wt3 = whd * lw[kw];
                u16 v[8] __attribute__((aligned(16)));
                *(uint4*)v = *(const uint4*)(base + (size_t)wz * 144);
                #pragma unroll
                for (int j = 0; j < 8; ++j) a[j] += wt3 * bf2f(v[j]);
            }
        }
    }
    const int c0 = c8 * 8;
    float* op = out + ((size_t)b * 144 + c0) * 4096 + od * 256 + oh * 16 + ow;
    #pragma unroll
    for (int j = 0; j < 8; ++j) op[(size_t)j * 4096] = a[j];
}

// ---------------------------------------------------------------------------
extern "C" void kernel_launch(void* const* d_in, const int* in_sizes, int n_in,
                              void* d_out, int out_size, void* d_ws, size_t ws_size,
                              hipStream_t stream) {
    const float* x  = (const float*)d_in[0];   // 4*72*32^3
    const float* W  = (const float*)d_in[1];   // 176*72*125
    const float* sb = (const float*)d_in[2];   // 16
    const float* gb = (const float*)d_in[3];   // 32
    float* out = (float*)d_out;                // 4*144*16^3 f32

    char* ws = (char*)d_ws;
    u16* xt = (u16*)(ws);                      // 18,874,368 B
    u16* wt = (u16*)(ws + 18874368);           //  3,379,200 B
    u16* zt = (u16*)(ws + 22253568);           // 37,748,736 B  (total ~60 MB)

    hipLaunchKernelGGL(k_transpose_x, dim3(4096), dim3(256), 0, stream, x, xt);
    hipLaunchKernelGGL(k_prep_w,      dim3(825),  dim3(256), 0, stream, W, wt);
    hipLaunchKernelGGL(k_conv,        dim3(1024), dim3(256), 0, stream, xt, wt, sb, gb, zt);
    hipLaunchKernelGGL(k_lowpass,     dim3(1152), dim3(256), 0, stream, zt, out);
}

// Round 6
// 538.579 us; speedup vs baseline: 1.7800x; 1.0601x over previous
//
#include <hip/hip_runtime.h>
#include <cstdint>
#include <cstddef>

typedef short short8 __attribute__((ext_vector_type(8)));
typedef float floatx4 __attribute__((ext_vector_type(4)));
typedef unsigned short u16;

__device__ __forceinline__ u16 f2bf(float f) {
    unsigned u = __float_as_uint(f);
    u += 0x7FFFu + ((u >> 16) & 1u);
    return (u16)(u >> 16);
}
__device__ __forceinline__ float bf2f(u16 h) {
    return __uint_as_float(((unsigned)h) << 16);
}

// async global->LDS, 16B per lane; LDS base must be wave-uniform (HW adds lane*16B).
__device__ __forceinline__ void gload_lds16(const u16* g, u16* l) {
    __builtin_amdgcn_global_load_lds(
        (const __attribute__((address_space(1))) void*)g,
        (__attribute__((address_space(3))) void*)l, 16, 0, 0);
}

// ---------------------------------------------------------------------------
// Kernel 1: x [4][72][32][32][32] f32 (NCDHW)  ->  xt [4][32][32][32][72] bf16
// ---------------------------------------------------------------------------
__global__ __launch_bounds__(256) void k_transpose_x(const float* __restrict__ x,
                                                     u16* __restrict__ xt) {
    __shared__ float tile[72 * 33];
    const int bx = blockIdx.x;               // ((b*32+d)*32+h)
    const int tid = threadIdx.x;
    const int b = bx >> 10, d = (bx >> 5) & 31, h = bx & 31;
    const float* src = x + (size_t)b * 72 * 32768 + d * 1024 + h * 32;
    for (int e = tid; e < 2304; e += 256) {
        int ci = e >> 5, w = e & 31;
        tile[ci * 33 + w] = src[(size_t)ci * 32768 + w];
    }
    __syncthreads();
    u16* dst = xt + (size_t)bx * 2304;
    for (int e = tid; e < 2304; e += 256) {
        int w = e / 72, ci = e - w * 72;
        dst[e] = f2bf(tile[ci * 33 + w]);
    }
}

// ---------------------------------------------------------------------------
// Kernel 2: W [176][72][5][5][5] f32 -> wt bf16 per-lane B-fragment layout:
//   wt[kd][kh][kblk(12)][nblk(11)][lane(64)][8]   (linear in kk = kh*12+kb)
// ---------------------------------------------------------------------------
__global__ __launch_bounds__(256) void k_prep_w(const float* __restrict__ W,
                                                u16* __restrict__ wt) {
    const int gid = blockIdx.x * 256 + threadIdx.x;   // 825*256 = 211200 = 3300 frags * 64
    const int frag = gid >> 6, lane = gid & 63;
    const int nb = frag % 11;
    int t = frag / 11;
    const int kb = t % 12;
    t = t / 12;
    const int kh = t % 5, kd = t / 5;
    const int n = lane & 15, q8 = (lane >> 4) * 8;
    const int co = nb * 16 + n;
    u16 v[8] __attribute__((aligned(16)));
    #pragma unroll
    for (int j = 0; j < 8; ++j) {
        int k = kb * 32 + q8 + j;
        u16 r = 0;
        if (k < 360) {
            int kw = k / 72, ci = k - kw * 72;
            r = f2bf(W[((size_t)co * 72 + ci) * 125 + kd * 25 + kh * 5 + kw]);
        }
        v[j] = r;
    }
    *(uint4*)(wt + (size_t)gid * 8) = *(const uint4*)v;
}

// ---------------------------------------------------------------------------
// Kernel 3: implicit-GEMM conv + fused gating, m201-style 2-barrier phases.
// Grid 256 = (b:4, d:32, ht:2), XCD-swizzled. Block: 512 threads = 8 waves.
// Block tile: 16 h-rows x 32 w x 176 co; wave: 2 h-rows x 32 w x 176 co.
// One phase per kb-step (60/kd):
//   vmcnt(4); s_barrier; sched_barrier;          <- counted, NEVER vmcnt(0)
//   15 ds_reads -> regs; STAGE(kk+3) (2 gloads/wave, uniform);
//   setprio(1); 44 MFMA; setprio(0); sched_barrier; s_barrier;
// B ring: 4 slots; phase kk reads slot kk&3, stages slot (kk+3)&3 (disjoint
// from slots being read at kk..kk+2). End-barrier bounds wave drift so the
// next phase's stage-writes can't race this phase's reads. Stages stay in
// flight 3 phases (~5000 cyc >> L2 latency): no drain stall anywhere.
// ---------------------------------------------------------------------------
#define LP 2624
#define MFMA_BF16 __builtin_amdgcn_mfma_f32_16x16x32_bf16

// Stage kb-step kk_ into ring slot slot_: 11 chunks of 1024B; uniform 2
// gloads/wave (waves dup-write chunks 8..10 with identical data - benign).
#define STAGE(kk_, slot_) do {                                                     \
    const int kks_ = (kk_) < 60 ? (kk_) : 0;   /* tail: dummy into dead slot */    \
    const u16* gs_ = wt_kd + (size_t)kks_ * 5632 + lane * 8;                       \
    u16* ds_ = sB + (slot_) * 5632;                                                \
    gload_lds16(gs_ + wv * 512, ds_ + wv * 512);                                   \
    gload_lds16(gs_ + c2w * 512, ds_ + c2w * 512);                                 \
} while (0)

#define PHASE(slot_) do {                                                          \
    asm volatile("s_waitcnt vmcnt(4)" ::: "memory");                               \
    __builtin_amdgcn_s_barrier();                                                  \
    __builtin_amdgcn_sched_barrier(0);                                             \
    const u16* ap_ = sx + (2 * wv + kh) * LP + laneA + kb * 32;                    \
    short8 A0_ = *(const short8*)(ap_);                                            \
    short8 A1_ = *(const short8*)(ap_ + 1152);                                     \
    short8 A2_ = *(const short8*)(ap_ + LP);                                       \
    short8 A3_ = *(const short8*)(ap_ + LP + 1152);                                \
    const u16* bb_ = sB + (slot_) * 5632 + lane * 8;                               \
    short8 bv_[11];                                                                \
    _Pragma("unroll")                                                              \
    for (int j = 0; j < 11; ++j) bv_[j] = *(const short8*)(bb_ + j * 512);         \
    STAGE(kk + 3, ((slot_) + 3) & 3);                                              \
    __builtin_amdgcn_s_setprio(1);                                                 \
    _Pragma("unroll")                                                              \
    for (int j = 0; j < 11; ++j) {                                                 \
        acc[0][j] = MFMA_BF16(A0_, bv_[j], acc[0][j], 0, 0, 0);                    \
        acc[1][j] = MFMA_BF16(A1_, bv_[j], acc[1][j], 0, 0, 0);                    \
        acc[2][j] = MFMA_BF16(A2_, bv_[j], acc[2][j], 0, 0, 0);                    \
        acc[3][j] = MFMA_BF16(A3_, bv_[j], acc[3][j], 0, 0, 0);                    \
    }                                                                              \
    __builtin_amdgcn_s_setprio(0);                                                 \
    __builtin_amdgcn_sched_barrier(0);                                             \
    __builtin_amdgcn_s_barrier();                                                  \
    ++kk;                                                                          \
    if (++kb == 12) { kb = 0; ++kh; }                                              \
} while (0)

__global__ __launch_bounds__(512, 2) void k_conv(const u16* __restrict__ xt,
                                                 const u16* __restrict__ wt,
                                                 const float* __restrict__ scalar_bias,
                                                 const float* __restrict__ gate_bias,
                                                 u16* __restrict__ zt) {
    __shared__ __align__(16) u16 sx[20 * LP];    // A tile: 16 out h + 4 halo (104,960 B)
    __shared__ __align__(16) u16 sB[4 * 5632];   // B ring: 4 x 11,264 B = 45,056 B
    const int bx = blockIdx.x;
    // XCD swizzle (256 = 8 XCD x 32): contiguous (b,d,ht) per XCD -> adjacent-d
    // blocks share 4/5 of their A d-slices in the same L2.
    const int swz = (bx & 7) * 32 + (bx >> 3);
    const int ht = swz & 1, d = (swz >> 1) & 31, b = swz >> 6;
    const int h0 = ht * 16;
    const int tid = threadIdx.x, lane = tid & 63, wv = tid >> 6;
    const int c15 = lane & 15, q = lane >> 4;
    const int c2w = 8 + wv % 3;                  // second stage chunk (8..10)

    floatx4 acc[4][11];
    #pragma unroll
    for (int i = 0; i < 4; ++i) {
        #pragma unroll
        for (int j = 0; j < 11; ++j) acc[i][j] = (floatx4){0.f, 0.f, 0.f, 0.f};
    }

    const int laneA = c15 * 72 + q * 8;

    for (int kd = 0; kd < 5; ++kd) {
        const int dp = d + kd - 2;
        if (dp < 0 || dp >= 32) continue;            // block-uniform
        const u16* wt_kd = wt + (size_t)kd * 5 * 67584;   // 12*11*512 u16 per (kd,kh)

        __syncthreads();   // waves done with prev kd's sx/sB; drains everything
        // ---- stage A d-slice into LDS (zero-fill halos & k-pad region) ----
        const u16* srcbase = xt + (size_t)((b * 32 + dp) * 32) * 2304;
        for (int idx = tid; idx < 20 * 328; idx += 512) {
            int r = idx / 328, c = idx - r * 328;
            int hp = h0 + r - 2;
            uint4 val = make_uint4(0u, 0u, 0u, 0u);
            if (hp >= 0 && hp < 32 && c >= 18 && c < 306)
                val = *(const uint4*)(srcbase + (size_t)hp * 2304 + (c * 8 - 144));
            *(uint4*)(&sx[r * LP + c * 8]) = val;
        }
        STAGE(0, 0);
        STAGE(1, 1);
        STAGE(2, 2);
        __syncthreads();   // full drain: sx + slots 0..2 ready

        int kk = 0, kh = 0, kb = 0;
        #pragma unroll 1
        for (int kp = 0; kp < 15; ++kp) {   // 15 x 4 = 60 phases, static slots
            PHASE(0);
            PHASE(1);
            PHASE(2);
            PHASE(3);
        }
    }

    // ---- epilogue: fused gate + bf16 store to zt ----
    // C/D layout: col(co) = lane&15, row(pos) = q*4 + reg.
    const float sb = scalar_bias[c15];
    int   slA[9];
    float gbA[9];
    #pragma unroll
    for (int nb = 1; nb <= 8; ++nb) {
        int idx = (nb - 1) * 16 + c15;                       // co_f - 16
        int mul = (nb <= 3) ? (idx / 3) : (16 + (idx - 48) / 5);
        slA[nb] = (lane & 48) | (mul & 15);
        gbA[nb] = gate_bias[mul];
    }
    #pragma unroll
    for (int mi = 0; mi < 4; ++mi) {
        const int hl = 2 * wv + (mi >> 1);
        const int wh = mi & 1;
        const size_t zrow0 = (size_t)((b * 32 + d) * 32 + (h0 + hl)) * 32;
        #pragma unroll
        for (int r = 0; r < 4; ++r) {
            const int w = wh * 16 + q * 4 + r;
            u16* zp = zt + (zrow0 + w) * 144;
            zp[c15] = f2bf(fmaxf(acc[mi][0][r] + sb, 0.f));   // scalar field: relu+bias
            const float g9v  = acc[mi][9][r];
            const float g10v = acc[mi][10][r];
            #pragma unroll
            for (int nb = 1; nb <= 8; ++nb) {
                float ys = __shfl((nb <= 3) ? g9v : g10v, slA[nb], 64);
                float g  = 1.f / (1.f + __expf(-(ys + gbA[nb])));
                zp[nb * 16 + c15] = f2bf(acc[mi][nb][r] * g);
            }
        }
    }
}

// ---------------------------------------------------------------------------
// Kernel 4: stride-2 5x5x5 Gaussian low-pass.
// zt [b][d][h][w][144] bf16 -> out [4][144][16][16][16] f32 (NCDHW).
// ---------------------------------------------------------------------------
__global__ __launch_bounds__(256) void k_lowpass(const u16* __restrict__ zt,
                                                 float* __restrict__ out) {
    const int gid = blockIdx.x * 256 + threadIdx.x;   // 1152*256 = 294912
    const int row = gid / 288;
    const int it  = gid - row * 288;
    const int c8 = it >> 4, ow = it & 15;
    const int oh = row & 15, od = (row >> 4) & 15, b = row >> 8;
    const float lw[5] = {0.03208210f, 0.23705644f, 0.46172277f, 0.23705644f, 0.03208210f};
    float a[8];
    #pragma unroll
    for (int j = 0; j < 8; ++j) a[j] = 0.f;
    for (int kd = 0; kd < 5; ++kd) {
        const int dz = 2 * od + kd - 2;
        if (dz < 0 || dz >= 32) continue;
        for (int kh = 0; kh < 5; ++kh) {
            const int hz = 2 * oh + kh - 2;
            if (hz < 0 || hz >= 32) continue;
            const float whd = lw[kd] * lw[kh];
            const u16* base = zt + (size_t)((b * 32 + dz) * 32 + hz) * 32 * 144 + c8 * 8;
            #pragma unroll
            for (int kw = 0; kw < 5; ++kw) {
                const int wz = 2 * ow + kw - 2;
                if (wz < 0 || wz >= 32) continue;
                const float wt3 = whd * lw[kw];
                u16 v[8] __attribute__((aligned(16)));
                *(uint4*)v = *(const uint4*)(base + (size_t)wz * 144);
                #pragma unroll
                for (int j = 0; j < 8; ++j) a[j] += wt3 * bf2f(v[j]);
            }
        }
    }
    const int c0 = c8 * 8;
    float* op = out + ((size_t)b * 144 + c0) * 4096 + od * 256 + oh * 16 + ow;
    #pragma unroll
    for (int j = 0; j < 8; ++j) op[(size_t)j * 4096] = a[j];
}

// ---------------------------------------------------------------------------
extern "C" void kernel_launch(void* const* d_in, const int* in_sizes, int n_in,
                              void* d_out, int out_size, void* d_ws, size_t ws_size,
                              hipStream_t stream) {
    const float* x  = (const float*)d_in[0];   // 4*72*32^3
    const float* W  = (const float*)d_in[1];   // 176*72*125
    const float* sb = (const float*)d_in[2];   // 16
    const float* gb = (const float*)d_in[3];   // 32
    float* out = (float*)d_out;                // 4*144*16^3 f32

    char* ws = (char*)d_ws;
    u16* xt = (u16*)(ws);                      // 18,874,368 B
    u16* wt = (u16*)(ws + 18874368);           //  3,379,200 B
    u16* zt = (u16*)(ws + 22253568);           // 37,748,736 B  (total ~60 MB)

    hipLaunchKernelGGL(k_transpose_x, dim3(4096), dim3(256), 0, stream, x, xt);
    hipLaunchKernelGGL(k_prep_w,      dim3(825),  dim3(256), 0, stream, W, wt);
    hipLaunchKernelGGL(k_conv,        dim3(256),  dim3(512), 0, stream, xt, wt, sb, gb, zt);
    hipLaunchKernelGGL(k_lowpass,     dim3(1152), dim3(256), 0, stream, zt, out);
}